// Round 20
// baseline (200.155 us; speedup 1.0000x reference)
//
#include <hip/hip_runtime.h>

typedef float v4f __attribute__((ext_vector_type(4)));

#define NPTS   4096
#define NB     8
#define QPT    16                  // queries per thread: block covers all 4096 preds
#define TPB    256
#define CHUNK  32                  // gts points per block (rm[] fits in registers)
#define NGRP   (CHUNK / 4)         // 8 groups of 4 points
#define NCHUNK (NPTS / CHUNK)      // 128
#define FINF   3.4e38f

// ---- order-preserving float <-> uint encoding (r7-proven atomicMin) ----
__device__ __forceinline__ unsigned enc_f(float f) {
    unsigned u = __float_as_uint(f);
    return (u & 0x80000000u) ? ~u : (u | 0x80000000u);
}
__device__ __forceinline__ float dec_f(unsigned e) {
    unsigned u = (e & 0x80000000u) ? (e ^ 0x80000000u) : ~e;
    return __uint_as_float(u);
}

// Fused chamfer: each block = (32-gts chunk, batch b) x ALL 4096 preds.
// Each distance is computed ONCE (134M instead of 268M): col-min (per pred,
// over the 32 staged gts) accumulates in acc[16] -> per-chunk partial store;
// row-min (per gts point, over ALL 4096 preds) accumulates in rm[32]
// REGISTERS (static indices via full unroll) -> 3-step shfl pre-reduce +
// encoded global atomicMin at kernel END (r11's fatal in-loop butterfly
// removed). 5.5 VALU ops per unique pair vs 8 for the two-pass scalar.
__global__ __launch_bounds__(TPB, 2) void fused_kernel(const float* __restrict__ preds,
                                                       const float* __restrict__ gts,
                                                       float* __restrict__ colpart,
                                                       unsigned* __restrict__ rowmins) {
    const int chunk = blockIdx.x;
    const int b     = blockIdx.y;
    const int tid   = threadIdx.x;
    const int lane  = tid & 63;

    __shared__ float SX[CHUNK], SY[CHUNK], SZ[CHUNK], SW[CHUNK];

    // ---- stage 32 gts points: (-2x, -2y, -2z, |p|^2) ----
    if (tid < CHUNK) {
        const float* pb = gts + ((size_t)b * NPTS + chunk * CHUNK) * 3;
        float x = pb[tid * 3 + 0];
        float y = pb[tid * 3 + 1];
        float z = pb[tid * 3 + 2];
        SX[tid] = -2.0f * x;
        SY[tid] = -2.0f * y;
        SZ[tid] = -2.0f * z;
        SW[tid] = fmaf(x, x, fmaf(y, y, z * z));
    }

    // ---- 16 preds per thread ----
    const float* qb = preds + (size_t)b * NPTS * 3;
    float qx[QPT], qy[QPT], qz[QPT], R[QPT], acc[QPT];
#pragma unroll
    for (int q = 0; q < QPT; ++q) {
        int j = q * TPB + tid;
        qx[q] = qb[j * 3 + 0];
        qy[q] = qb[j * 3 + 1];
        qz[q] = qb[j * 3 + 2];
        R[q]  = fmaf(qx[q], qx[q], fmaf(qy[q], qy[q], qz[q] * qz[q]));
        acc[q] = FINF;
    }
    float rm[CHUNK];
#pragma unroll
    for (int i = 0; i < CHUNK; ++i) rm[i] = FINF;
    __syncthreads();

    const v4f* SXv = (const v4f*)SX;
    const v4f* SYv = (const v4f*)SY;
    const v4f* SZv = (const v4f*)SZ;
    const v4f* SWv = (const v4f*)SW;

    // ---- main loop: 4 gts x 16 preds per group; t = |p|^2 - 2 p.q ----
#pragma unroll
    for (int g = 0; g < NGRP; ++g) {
        const v4f X = SXv[g], Y = SYv[g], Z = SZv[g], W = SWv[g];
#pragma unroll
        for (int q = 0; q < QPT; ++q) {
            float t0 = fmaf(X.x, qx[q], fmaf(Y.x, qy[q], fmaf(Z.x, qz[q], W.x)));
            float t1 = fmaf(X.y, qx[q], fmaf(Y.y, qy[q], fmaf(Z.y, qz[q], W.y)));
            float t2 = fmaf(X.z, qx[q], fmaf(Y.z, qy[q], fmaf(Z.z, qz[q], W.z)));
            float t3 = fmaf(X.w, qx[q], fmaf(Y.w, qy[q], fmaf(Z.w, qz[q], W.w)));
            acc[q] = fminf(acc[q], fminf(fminf(t0, t1), fminf(t2, t3)));   // col
            rm[4 * g + 0] = fminf(rm[4 * g + 0], t0 + R[q]);               // row
            rm[4 * g + 1] = fminf(rm[4 * g + 1], t1 + R[q]);
            rm[4 * g + 2] = fminf(rm[4 * g + 2], t2 + R[q]);
            rm[4 * g + 3] = fminf(rm[4 * g + 3], t3 + R[q]);
        }
    }

    // ---- col partials: unique slots, coalesced (r10-proven) ----
    float* cdst = colpart + ((size_t)(b * NCHUNK + chunk)) * NPTS;
#pragma unroll
    for (int q = 0; q < QPT; ++q) {
        cdst[q * TPB + tid] = acc[q] + R[q];
    }

    // ---- row-mins: 3-step shfl pre-reduce (8 lanes) + encoded atomicMin ----
    unsigned* rdst = rowmins + (size_t)b * NPTS + chunk * CHUNK;
#pragma unroll
    for (int i = 0; i < CHUNK; ++i) {
        float v = rm[i];
        v = fminf(v, __shfl_xor(v, 1, 64));
        v = fminf(v, __shfl_xor(v, 2, 64));
        v = fminf(v, __shfl_xor(v, 4, 64));
        if ((lane & 7) == 0) atomicMin(&rdst[i], enc_f(v));
    }
}

// Tail: thread s handles pred j (fold 128 col partials + huber) AND gts point
// (decode final row-min + huber). Deterministic block partial-sum.
__global__ __launch_bounds__(256) void huber_kernel(const float* __restrict__ colpart,
                                                    const unsigned* __restrict__ rowmins,
                                                    const float* __restrict__ cp,
                                                    float* __restrict__ bp) {
    const int s = blockIdx.x * 256 + threadIdx.x;   // [0, NB*NPTS)
    const int b = s >> 12, j = s & (NPTS - 1);
    const float* p = colpart + ((size_t)b * NCHUNK) * NPTS + j;
    float m1 = FINF;
#pragma unroll 8
    for (int c = 0; c < NCHUNK; ++c) m1 = fminf(m1, p[(size_t)c * NPTS]);
    float m2 = dec_f(rowmins[s]);
    const float cc = cp[0];
    float h1 = (m1 < cc) ? (0.5f * m1 * m1) : fmaf(cc, m1, -0.5f * cc * cc);
    float h2 = (m2 < cc) ? (0.5f * m2 * m2) : fmaf(cc, m2, -0.5f * cc * cc);
    float h = h1 + h2;
    for (int off = 32; off > 0; off >>= 1) h += __shfl_down(h, off, 64);
    __shared__ float ls[4];
    if ((threadIdx.x & 63) == 0) ls[threadIdx.x >> 6] = h;
    __syncthreads();
    if (threadIdx.x == 0) bp[blockIdx.x] = ls[0] + ls[1] + ls[2] + ls[3];
}

__global__ __launch_bounds__(128) void final_kernel(const float* __restrict__ bp,
                                                    float* __restrict__ out) {
    float a = bp[threadIdx.x];   // exactly 128 block partials
    for (int off = 32; off > 0; off >>= 1) a += __shfl_down(a, off, 64);
    __shared__ float ls[2];
    if ((threadIdx.x & 63) == 0) ls[threadIdx.x >> 6] = a;
    __syncthreads();
    if (threadIdx.x == 0) out[0] = ls[0] + ls[1];
}

extern "C" void kernel_launch(void* const* d_in, const int* in_sizes, int n_in,
                              void* d_out, int out_size, void* d_ws, size_t ws_size,
                              hipStream_t stream) {
    const float* preds = (const float*)d_in[0];  // [8, 4096, 3]
    const float* gts   = (const float*)d_in[1];  // [8, 4096, 3]
    const float* cp    = (const float*)d_in[2];  // [1]
    float* out = (float*)d_out;

    unsigned* rowmins = (unsigned*)d_ws;                       // [8][4096] = 128 KB
    float*    colpart = (float*)(rowmins + (size_t)NB * NPTS); // [8][128][4096] = 16 MB
    float*    bp      = colpart + (size_t)NB * NCHUNK * NPTS;  // [128]

    // 0xFF bytes == encoded +inf (r8-proven capture-safe)
    hipMemsetAsync(rowmins, 0xFF, (size_t)NB * NPTS * sizeof(unsigned), stream);

    dim3 gm(NCHUNK, NB);   // (128, 8) = 1024 blocks
    fused_kernel<<<gm, TPB, 0, stream>>>(preds, gts, colpart, rowmins);

    huber_kernel<<<(NB * NPTS) / 256, 256, 0, stream>>>(colpart, rowmins, cp, bp);
    final_kernel<<<1, 128, 0, stream>>>(bp, out);
}

// Round 21
// 32.104 us; speedup vs baseline: 6.2346x; 6.2346x over previous
//
#include <hip/hip_runtime.h>

typedef float v4f __attribute__((ext_vector_type(4)));

#define NPTS   4096
#define NZ     16                  // B * 2 passes
#define QPT    16                  // queries per thread: one block covers all 4096
#define TPB    256
#define CHUNK  128                 // points staged per block
#define NGRP   (CHUNK / 4)         // 32 groups of 4 points
#define NCHUNK (NPTS / CHUNK)      // 32

__device__ __forceinline__ float min3f(float a, float b, float c) {
    float d;
    asm("v_min3_f32 %0, %1, %2, %3" : "=v"(d) : "v"(a), "v"(b), "v"(c));
    return d;
}

// blockIdx: x = point chunk (32), y = b*2 + pass (16). 512 blocks, 2/CU.
// QPT=16 (4 ds_read_b128 serve 64 pairs) + depth-1 group prefetch. Best
// measured configuration of the two-pass scalar structure (31.98us, absmax 0).
// Session evidence: min phase ~28us ~= 75% of the practical scalar-VALU
// ceiling; MFMA (r14-16), fusion (r11, r20), packed f32 (r9), occupancy
// (r3/r12/r13), desync (r17), asm-free scheduling (r19) all explored and
// bounded. This is the floor for this decomposition.
__global__ __launch_bounds__(TPB, 2) void min_kernel(const float* __restrict__ preds,
                                                     const float* __restrict__ gts,
                                                     float* __restrict__ partial) {
    const int z    = blockIdx.y;
    const int b    = z >> 1;
    const int pass = z & 1;
    const int tid  = threadIdx.x;

    const float* pts = pass ? preds : gts;   // pass0: min over gts (per pred)
    const float* qrs = pass ? gts   : preds; // pass1: min over preds (per gt)

    __shared__ float SX[CHUNK], SY[CHUNK], SZ[CHUNK], SW[CHUNK];

    // ---- stage CHUNK points, SoA (+|p|^2) ----
    {
        const float* pb = pts + ((size_t)b * NPTS + blockIdx.x * CHUNK) * 3;
        if (tid < CHUNK) {
            float x  = pb[tid * 3 + 0];
            float y  = pb[tid * 3 + 1];
            float zz = pb[tid * 3 + 2];
            SX[tid] = x;
            SY[tid] = y;
            SZ[tid] = zz;
            SW[tid] = fmaf(x, x, fmaf(y, y, zz * zz));
        }
    }

    // ---- per-thread queries (16: whole 4096 covered by the block) ----
    const float* qb = qrs + (size_t)b * NPTS * 3;
    float ax[QPT], ay[QPT], az[QPT], R[QPT], acc[QPT];
#pragma unroll
    for (int q = 0; q < QPT; ++q) {
        int   j  = q * TPB + tid;
        float qx = qb[j * 3 + 0];
        float qy = qb[j * 3 + 1];
        float qz = qb[j * 3 + 2];
        R[q]  = fmaf(qx, qx, fmaf(qy, qy, qz * qz));
        ax[q] = -2.0f * qx;
        ay[q] = -2.0f * qy;
        az[q] = -2.0f * qz;
        acc[q] = 3.4e38f;
    }
    __syncthreads();

    const v4f* SXv = (const v4f*)SX;
    const v4f* SYv = (const v4f*)SY;
    const v4f* SZv = (const v4f*)SZ;
    const v4f* SWv = (const v4f*)SW;

    // ---- main loop with depth-1 prefetch: load g+1 before computing g ----
    v4f Xn = SXv[0], Yn = SYv[0], Zn = SZv[0], Wn = SWv[0];
#pragma unroll 1
    for (int g = 0; g < NGRP; ++g) {
        const v4f X = Xn, Y = Yn, Z = Zn, W = Wn;
        const int gn = (g + 1) & (NGRP - 1);   // wrap: benign re-read, no branch
        Xn = SXv[gn]; Yn = SYv[gn]; Zn = SZv[gn]; Wn = SWv[gn];
#pragma unroll
        for (int q = 0; q < QPT; ++q) {
            float t0 = fmaf(X.x, ax[q], fmaf(Y.x, ay[q], fmaf(Z.x, az[q], W.x)));
            float t1 = fmaf(X.y, ax[q], fmaf(Y.y, ay[q], fmaf(Z.y, az[q], W.y)));
            float t2 = fmaf(X.z, ax[q], fmaf(Y.z, ay[q], fmaf(Z.z, az[q], W.z)));
            float t3 = fmaf(X.w, ax[q], fmaf(Y.w, ay[q], fmaf(Z.w, az[q], W.w)));
            acc[q] = min3f(t0, t1, min3f(t2, t3, acc[q]));
        }
    }

    // ---- store per-(z,chunk) partial mins (unique slots, coalesced) ----
    float* dst = partial + ((size_t)z * NCHUNK + blockIdx.x) * NPTS;
#pragma unroll
    for (int q = 0; q < QPT; ++q) {
        dst[q * TPB + tid] = R[q] + acc[q];
    }
}

// min over the NCHUNK partials per query, huber, block partial-sum.
__global__ __launch_bounds__(256) void huber_kernel(const float* __restrict__ partial,
                                                    const float* __restrict__ cp,
                                                    float* __restrict__ bp) {
    const int s = blockIdx.x * 256 + threadIdx.x;   // [0, NZ*NPTS)
    const int z = s >> 12, j = s & (NPTS - 1);
    const float* p = partial + (size_t)z * NCHUNK * NPTS + j;
    float m = 3.4e38f;
#pragma unroll
    for (int c = 0; c < NCHUNK; ++c) m = fminf(m, p[(size_t)c * NPTS]);
    const float cc = cp[0];
    float h = (m < cc) ? (0.5f * m * m) : fmaf(cc, m, -0.5f * cc * cc);
    for (int off = 32; off > 0; off >>= 1) h += __shfl_down(h, off, 64);
    __shared__ float ls[4];
    if ((threadIdx.x & 63) == 0) ls[threadIdx.x >> 6] = h;
    __syncthreads();
    if (threadIdx.x == 0) bp[blockIdx.x] = ls[0] + ls[1] + ls[2] + ls[3];
}

__global__ __launch_bounds__(256) void final_kernel(const float* __restrict__ bp,
                                                    float* __restrict__ out) {
    float a = bp[threadIdx.x];   // exactly 256 block partials
    for (int off = 32; off > 0; off >>= 1) a += __shfl_down(a, off, 64);
    __shared__ float ls[4];
    if ((threadIdx.x & 63) == 0) ls[threadIdx.x >> 6] = a;
    __syncthreads();
    if (threadIdx.x == 0) out[0] = ls[0] + ls[1] + ls[2] + ls[3];
}

extern "C" void kernel_launch(void* const* d_in, const int* in_sizes, int n_in,
                              void* d_out, int out_size, void* d_ws, size_t ws_size,
                              hipStream_t stream) {
    const float* preds = (const float*)d_in[0];  // [8, 4096, 3]
    const float* gts   = (const float*)d_in[1];  // [8, 4096, 3]
    const float* cp    = (const float*)d_in[2];  // [1]
    float* out = (float*)d_out;

    float* partial = (float*)d_ws;                           // [NZ][NCHUNK][NPTS] = 8 MB
    float* bp      = partial + (size_t)NZ * NCHUNK * NPTS;   // [256]

    dim3 gm(NCHUNK, NZ);   // (32, 16) = 512 blocks
    min_kernel<<<gm, TPB, 0, stream>>>(preds, gts, partial);

    huber_kernel<<<(NZ * NPTS) / 256, 256, 0, stream>>>(partial, cp, bp);
    final_kernel<<<1, 256, 0, stream>>>(bp, out);
}